// Round 6
// baseline (259.496 us; speedup 1.0000x reference)
//
#include <hip/hip_runtime.h>
#include <math.h>

// Problem constants (fixed by reference)
#define B_TOT   256
#define N_TOT   2304
#define IN_DIM  8
#define NC      10      // NUM_CLASSES
#define OD      16      // OUT_DIM
#define CD      160     // NC*OD
#define RBIAS   0.1f

// R6 geometry: R3's proven 512-block CU-paired layout (2 blocks/CU, the two
// blocks on a CU share the same n-range -> W lines shared in L1/L2).
#define BTILE    64                      // b per block (= wave lanes)
#define NS       128                     // n-slices
#define NPB      (N_TOT / NS)            // 18 n per block
#define NTHREADS 640                     // 10 waves
#define XR       (NPB * IN_DIM + 4)      // 148: x row stride
#define LB       72                      // logit board row stride
#define NF4      (B_TOT * CD / 4)        // 10240 float4 per partial slab
#define WROW     (IN_DIM * CD)           // 1280 floats per W row

#define NXCD     8

// Reduce: 1280 blocks × 256 thr = 5 blk/CU balanced
#define RCOLS    8
#define RGRPS    32
#define RYPER    (NS / RGRPS)            // 4

// ===== Routing round, R6: W fan-out via v_readlane (VALU broadcast).
// R5 post-mortem: LDS pipe 100% saturated -- 34 broadcast ds_read_b128 per
// wave-nn at 12.4cy each = measured 63us exactly; broadcast b128 delivers
// 16 useful bytes at the cost of 1024. The CU has ONE LDS pipe but FOUR
// VALU pipes at 40% idle. New W transport:
//   lane l global-loads float2 = W[n][l>>3][c*16 + 2*(l&7) + {0,1}]
//   (one coalesced dwordx2 per wave per nn, L2-local via XCD swizzle),
//   then 128x { v_readlane const-lane -> SGPR; v_fma with SGPR operand }.
// LDS keeps only x tile + logit board. Round 0 has NO per-nn barriers.
// FMA order identical to R5 (u=0; i=0..7 fmaf, d ascending) -> bit-identical.
template <int FIRST>
__global__ __launch_bounds__(NTHREADS, 5) void routing_round(
    const float* __restrict__ x,      // [B, N, 8]
    const float* __restrict__ W,      // [N, 8, 160]
    const float* __restrict__ S_acc,  // [B, 160]
    float* __restrict__ part)         // [NS, B, 160]
{
    __shared__ __align__(16) float sh_x[BTILE * XR];   // 37.9 KB
    __shared__ float sh_lg[2][NC * LB];                // 5.8 KB
    // total 43.7 KB -> 2 blocks/CU (87.4 < 160 KB)

    const int tid = threadIdx.x;

    // R3's CU-pair map: xcd = o&7 (round-robin over XCDs); within-XCD rank
    // r = o>>3; breadth-first fill puts ranks r and r+32 on the same CU ->
    // give them the same (y, n-range), different b0. W slice/XCD = 1.4 MB.
    const int o      = blockIdx.x;                 // 0..511
    const int xcd    = o & (NXCD - 1);
    const int r      = o >> 3;                     // 0..63
    const int cuslot = r & 31;
    const int pairid = r >> 5;                     // the two blocks on a CU
    const int ySlab  = xcd * 16 + (cuslot & 15);   // 0..127
    const int b0     = ((cuslot >> 4) * 2 + pairid) * BTILE;
    const int n0     = ySlab * NPB;

    const int b   = tid & 63;
    const int cu  = __builtin_amdgcn_readfirstlane(tid >> 6);

    // per-lane W slice pointer: lane l holds (i = l>>3, d = 2*(l&7)+{0,1})
    const float* Wl = W + (size_t)cu * OD + (b >> 3) * CD + (b & 7) * 2;

    // prologue W load (row n0) — issued before x staging for latency cover
    float2 wc = *(const float2*)(Wl + (size_t)n0 * WROW);

    // ---- stage x tile: [64 b][144 floats], coalesced float4
    {
        const int XT4 = BTILE * (NPB * IN_DIM / 4);   // 2304
        for (int k = tid; k < XT4; k += NTHREADS) {
            int bb   = k / (NPB * 2);
            int off4 = k - bb * (NPB * 2);
            float4 v = *(const float4*)(x + ((size_t)(b0 + bb) * N_TOT + n0) * IN_DIM + off4 * 4);
            *(float4*)(&sh_x[bb * XR + off4 * 4]) = v;
        }
    }

    // ---- S fragment: all 16 d for (b, c)
    float S[OD];
    if (!FIRST) {
        const float4* sp = (const float4*)(S_acc + (size_t)(b0 + b) * CD + cu * OD);
        #pragma unroll
        for (int q = 0; q < 4; q++) ((float4*)S)[q] = sp[q];
    }

    float acc[OD];
    #pragma unroll
    for (int d = 0; d < OD; d++) acc[d] = 0.f;

    __syncthreads();   // sh_x ready

    for (int nn = 0; nn < NPB; nn++) {
        const int cur = nn & 1;

        // software-pipelined next-row W load: issued here, consumed next nn;
        // latency hidden under the 256-VALU block below. No manual vmcnt.
        float2 wn;
        if (nn + 1 < NPB) wn = *(const float2*)(Wl + (size_t)(n0 + nn + 1) * WROW);
        else              wn = wc;

        float xf[IN_DIM];
        {
            const float4* xp = (const float4*)(&sh_x[b * XR + nn * IN_DIM]);
            ((float4*)xf)[0] = xp[0];
            ((float4*)xf)[1] = xp[1];
        }

        // u = x . W — W broadcast via v_readlane (const lane) -> SGPR -> FMA.
        // Order identical to R5: u=0, i outer 0..7, d inner ascending.
        float u[OD];
        #pragma unroll
        for (int d = 0; d < OD; d++) u[d] = 0.f;
        const int wxi = __float_as_int(wc.x);
        const int wyi = __float_as_int(wc.y);
        #pragma unroll
        for (int i = 0; i < IN_DIM; i++) {
            const float xi = xf[i];
            #pragma unroll
            for (int dp = 0; dp < 8; dp++) {
                const float w0 = __int_as_float(__builtin_amdgcn_readlane(wxi, i * 8 + dp));
                const float w1 = __int_as_float(__builtin_amdgcn_readlane(wyi, i * 8 + dp));
                u[2 * dp]     = fmaf(xi, w0, u[2 * dp]);
                u[2 * dp + 1] = fmaf(xi, w1, u[2 * dp + 1]);
            }
        }

        if (!FIRST) {
            float lg = 0.f;
            #pragma unroll
            for (int d = 0; d < OD; d++) lg = fmaf(u[d], S[d], lg);
            sh_lg[cur][cu * LB + b] = lg;
            __syncthreads();   // logit board only (W is in registers now)

            float m = -1e30f;
            float row[NC];
            #pragma unroll
            for (int k = 0; k < NC; k++) {
                row[k] = sh_lg[cur][k * LB + b];
                m = fmaxf(m, row[k]);
            }
            float den = 0.f;
            #pragma unroll
            for (int k = 0; k < NC; k++) den += __expf(row[k] - m);
            float cw = __expf(lg - m) / den;

            #pragma unroll
            for (int d = 0; d < OD; d++) acc[d] = fmaf(cw, u[d], acc[d]);
        } else {
            #pragma unroll
            for (int d = 0; d < OD; d++) acc[d] += u[d];
            // no barrier at all in round 0
        }

        wc = wn;
    }

    float* dst = part + ((size_t)ySlab * B_TOT + (b0 + b)) * CD + cu * OD;
    #pragma unroll
    for (int q = 0; q < 4; q++)
        ((float4*)dst)[q] = ((float4*)acc)[q];
}

// ===== Full-device merged reduce: 1280 blocks × 256 threads = 5 blk/CU.
// Block owns 8 float4-columns; thread (col, grp) sums 4 slabs (y = grp+32k);
// LDS combine; threads 0..7 apply scale/bias + stage B:
// store S_acc (round 0 — no memset), add (round 1), squash -> v_out (round 2).
__global__ __launch_bounds__(256) void reduce_round(
    const float* __restrict__ part,   // [NS, B, 160]
    float* __restrict__ S_acc,        // [B, 160]
    float* __restrict__ v_out,        // [B, 10, 16]
    float scale, int round)
{
    __shared__ float4 sh[RGRPS][RCOLS];   // 4 KB

    const int col = threadIdx.x & (RCOLS - 1);
    const int grp = threadIdx.x >> 3;               // 0..31
    const int g   = blockIdx.x * RCOLS + col;       // float4 column index

    const float4* p4 = (const float4*)part + (size_t)grp * NF4 + g;
    float4 s = { 0.f, 0.f, 0.f, 0.f };
    #pragma unroll
    for (int y = 0; y < RYPER; y++) {               // slabs grp, grp+32, ...
        float4 t = p4[(size_t)y * RGRPS * NF4];
        s.x += t.x; s.y += t.y; s.z += t.z; s.w += t.w;
    }
    sh[grp][col] = s;
    __syncthreads();

    if (threadIdx.x < RCOLS) {
        float4 t = { 0.f, 0.f, 0.f, 0.f };
        #pragma unroll
        for (int k = 0; k < RGRPS; k++) {
            float4 q = sh[k][col];
            t.x += q.x; t.y += q.y; t.z += q.z; t.w += q.w;
        }
        t.x = t.x * scale + RBIAS;
        t.y = t.y * scale + RBIAS;
        t.z = t.z * scale + RBIAS;
        t.w = t.w * scale + RBIAS;

        if (round == 0) {
            ((float4*)S_acc)[g] = t;          // store — no memset required
        } else if (round == 1) {
            float4 o = ((float4*)S_acc)[g];
            o.x += t.x; o.y += t.y; o.z += t.z; o.w += t.w;
            ((float4*)S_acc)[g] = o;
        } else {
            // squash: 16 d = 4 consecutive float4 columns = lanes 4k..4k+3
            float ss = t.x * t.x + t.y * t.y + t.z * t.z + t.w * t.w;
            ss += __shfl_xor(ss, 1, 64);
            ss += __shfl_xor(ss, 2, 64);
            float norm = sqrtf(ss);
            float k2 = norm / (1.0f + ss);
            float4 v = { t.x * k2, t.y * k2, t.z * k2, t.w * k2 };
            ((float4*)v_out)[g] = v;
        }
    }
}

extern "C" void kernel_launch(void* const* d_in, const int* in_sizes, int n_in,
                              void* d_out, int out_size, void* d_ws, size_t ws_size,
                              hipStream_t stream) {
    const float* x = (const float*)d_in[0];   // [256,2304,8]
    const float* W = (const float*)d_in[1];   // [2304,8,160]
    float* out = (float*)d_out;               // [256,10,16]

    // Workspace (every byte written before read each call — re-poison safe)
    float* part  = (float*)d_ws;                            // NS * 40960  (~21 MB)
    float* S_acc = part + (size_t)NS * B_TOT * CD;          // 40960 floats

    const dim3 rgrid(NS * (B_TOT / BTILE));   // 512 blocks = 2/CU paired
    const int  RG = NF4 / RCOLS;              // 1280 reduce blocks — 5/CU

    // Round 0 (uniform cw; 0.1 folded into reduce scale; S_acc stored not added)
    routing_round<1><<<rgrid, NTHREADS, 0, stream>>>(x, W, S_acc, part);
    reduce_round<<<RG, 256, 0, stream>>>(part, S_acc, out, 0.1f, 0);

    // Round 1
    routing_round<0><<<rgrid, NTHREADS, 0, stream>>>(x, W, S_acc, part);
    reduce_round<<<RG, 256, 0, stream>>>(part, S_acc, out, 1.0f, 1);

    // Round 2 (+final squash fused)
    routing_round<0><<<rgrid, NTHREADS, 0, stream>>>(x, W, S_acc, part);
    reduce_round<<<RG, 256, 0, stream>>>(part, S_acc, out, 1.0f, 2);
}